// Round 3
// baseline (191.610 us; speedup 1.0000x reference)
//
#include <hip/hip_runtime.h>

// ---- types ----
typedef __attribute__((ext_vector_type(8))) short  bf16x8;  // 8 bf16 = 4 VGPR
typedef __attribute__((ext_vector_type(4))) float  f32x4;

static __device__ __forceinline__ unsigned short f2bf(float f) {
    unsigned u = __float_as_uint(f);
    u += 0x7fffu + ((u >> 16) & 1u);      // RNE (inputs are finite)
    return (unsigned short)(u >> 16);
}

// ---------------------------------------------------------------------------
// Prep: At[bn][n][k] = bf16(A[bn][k][n]); 32*128*128 bf16 = 1 MB into d_ws.
// ---------------------------------------------------------------------------
__global__ __launch_bounds__(256) void prep_at_kernel(
        const float* __restrict__ A, unsigned short* __restrict__ At)
{
    int g   = blockIdx.x * 256 + threadIdx.x;   // 65536 total
    int bn  = g >> 11;
    int rem = g & 2047;
    int kc  = rem >> 7;                         // k octet
    int n   = rem & 127;

    const float* src = A + bn * 16384 + kc * 8 * 128 + n;
    unsigned h[4];
    #pragma unroll
    for (int j = 0; j < 4; ++j) {
        unsigned short lo = f2bf(src[(2 * j    ) * 128]);
        unsigned short hi = f2bf(src[(2 * j + 1) * 128]);
        h[j] = (unsigned)lo | ((unsigned)hi << 16);
    }
    uint4 pk = make_uint4(h[0], h[1], h[2], h[3]);
    *(uint4*)(At + bn * 16384 + n * 128 + kc * 8) = pk;
}

// ---------------------------------------------------------------------------
// Main: grid 1024 (bn = blk>>5 fixed per block -> At block in registers
// once). 512 threads = 8 waves; wave (wm=wid>>2, wn=wid&3) owns 16 rows x
// 32 cols of each 32x128 tile. LDS: double-buffered 32x128 f32 tile
// (2 x 16 KB = 32 KB/block). __launch_bounds__(512, 8) pins VGPR <= 64 so
// 8 waves/SIMD = 4 blocks/CU co-resident (VGPR quantum steps at 64/128/256)
// -> staggered load bursts keep HBM pipe busy across barriers.
// XOR-swizzle (row&7)<<4 applied BOTH on pre-swizzled global source and on
// the ds_read byte offset (both-or-neither rule for global_load_lds).
// ---------------------------------------------------------------------------
__global__ __launch_bounds__(512, 8) void trans_main_kernel(
        const float* __restrict__ v,  const float* __restrict__ dx,
        const unsigned short* __restrict__ At, const float* __restrict__ Bm,
        const float* __restrict__ bsc, float* __restrict__ out)
{
    __shared__ float lds[2][32 * 128];          // 32 KB

    const int tid = threadIdx.x;
    const int wid = tid >> 6;
    const int l   = tid & 63;
    const int lr  = l & 15;
    const int lq  = l >> 4;
    const int wm  = wid >> 2;                   // 0..1 (16-row half)
    const int wn  = wid & 3;                    // 0..3 (32-col quarter)
    const int bn     = blockIdx.x >> 5;         // 0..31
    const int mtbase = blockIdx.x & 31;

    // ---- At block -> registers, once. b-frag: B[k=lq*8+j][n=col] ----
    bf16x8 bq[4][2];
    const unsigned short* atb = At + bn * 16384 + (wn * 32 + lr) * 128 + lq * 8;
    #pragma unroll
    for (int kq = 0; kq < 4; ++kq)
        #pragma unroll
        for (int ni = 0; ni < 2; ++ni)
            bq[kq][ni] = *(const bf16x8*)(atb + ni * 16 * 128 + kq * 32);

    // ---- epilogue constants (bn fixed for whole block) ----
    const float bias = *bsc;
    const int col0 = bn * 128 + wn * 32;
    float2 bc[2];
    #pragma unroll
    for (int ni = 0; ni < 2; ++ni)
        bc[ni] = *(const float2*)(Bm + 2 * (col0 + ni * 16 + lr));

    // ---- async stage of one 32x128 tile (pre-swizzled source) ----
    auto stage = [&](int buf, int mt) {
        const float* src = v + (size_t)mt * 32 * 4096 + bn * 128;
        #pragma unroll
        for (int it = 0; it < 2; ++it) {
            int c16  = it * 512 + tid;          // 16B-chunk index in tile
            int row  = c16 >> 5;                // 32 chunks per 512B row
            int off  = (c16 & 31) << 4;         // byte offset within row
            int soff = off ^ ((row & 7) << 4);  // inverse-swizzled source
            const float* g = src + (size_t)row * 4096 + (soff >> 2);
            __builtin_amdgcn_global_load_lds(
                (const __attribute__((address_space(1))) unsigned int*)g,
                (__attribute__((address_space(3))) unsigned int*)
                    &lds[buf][c16 * 4],
                16, 0, 0);
        }
    };

    f32x4 acc[2];
    #pragma unroll
    for (int ni = 0; ni < 2; ++ni)
        acc[ni] = (f32x4){0.f, 0.f, 0.f, 0.f};

    stage(0, mtbase);
    __syncthreads();                            // buf0 ready

    for (int j = 0; j < 16; ++j) {
        const int mt = j * 32 + mtbase;
        if (j + 1 < 16) stage((j + 1) & 1, (j + 1) * 32 + mtbase);

        // ---- compute from lds[j&1] ----
        const char* Lb = (const char*)&lds[j & 1][0];
        const int row = wm * 16 + lr;
        const int rb  = row * 512;
        const int m   = (row & 7) << 4;
        #pragma unroll
        for (int kq = 0; kq < 4; ++kq) {
            const int base = kq * 128 + lq * 32;
            float4 f0 = *(const float4*)(Lb + rb + ((base     ) ^ m));
            float4 f1 = *(const float4*)(Lb + rb + ((base + 16) ^ m));
            union { bf16x8 vv; unsigned short s[8]; } u;
            u.s[0] = f2bf(f0.x); u.s[1] = f2bf(f0.y);
            u.s[2] = f2bf(f0.z); u.s[3] = f2bf(f0.w);
            u.s[4] = f2bf(f1.x); u.s[5] = f2bf(f1.y);
            u.s[6] = f2bf(f1.z); u.s[7] = f2bf(f1.w);
            acc[0] = __builtin_amdgcn_mfma_f32_16x16x32_bf16(
                         u.vv, bq[kq][0], acc[0], 0, 0, 0);
            acc[1] = __builtin_amdgcn_mfma_f32_16x16x32_bf16(
                         u.vv, bq[kq][1], acc[1], 0, 0, 0);
        }

        // ---- epilogue: + dx @ B^T + b, ReLU, store; reset acc ----
        #pragma unroll
        for (int jj = 0; jj < 4; ++jj) {
            const int rowg = mt * 32 + wm * 16 + lq * 4 + jj;
            const float2 d = *(const float2*)(dx + 2 * rowg);
            float* orow = out + (size_t)rowg * 4096 + col0 + lr;
            float v0 = acc[0][jj] + d.x * bc[0].x + d.y * bc[0].y + bias;
            float v1 = acc[1][jj] + d.x * bc[1].x + d.y * bc[1].y + bias;
            orow[0]  = fmaxf(v0, 0.0f);
            orow[16] = fmaxf(v1, 0.0f);
        }
        #pragma unroll
        for (int ni = 0; ni < 2; ++ni)
            acc[ni] = (f32x4){0.f, 0.f, 0.f, 0.f};

        __syncthreads();    // all reads of lds[j&1] done; next stage complete
    }
}

// ---------------------------------------------------------------------------
extern "C" void kernel_launch(void* const* d_in, const int* in_sizes, int n_in,
                              void* d_out, int out_size, void* d_ws, size_t ws_size,
                              hipStream_t stream)
{
    const float* v  = (const float*)d_in[0];   // [16384, 4096]
    const float* dx = (const float*)d_in[1];   // [16384, 2]
    const float* A  = (const float*)d_in[2];   // [32, 128, 128]
    const float* Bm = (const float*)d_in[3];   // [4096, 2]
    const float* b  = (const float*)d_in[4];   // scalar

    unsigned short* At = (unsigned short*)d_ws; // 1 MB: [32][128 n][128 k] bf16

    prep_at_kernel<<<dim3(256), dim3(256), 0, stream>>>(A, At);
    trans_main_kernel<<<dim3(1024), dim3(512), 0, stream>>>(v, dx, At, Bm, b,
                                                            (float*)d_out);
}

// Round 4
// 150.165 us; speedup vs baseline: 1.2760x; 1.2760x over previous
//
#include <hip/hip_runtime.h>

// ---- types ----
typedef __attribute__((ext_vector_type(8))) short  bf16x8;  // 8 bf16 = 4 VGPR
typedef __attribute__((ext_vector_type(4))) float  f32x4;

static __device__ __forceinline__ unsigned short f2bf(float f) {
    unsigned u = __float_as_uint(f);
    u += 0x7fffu + ((u >> 16) & 1u);      // RNE (inputs are finite)
    return (unsigned short)(u >> 16);
}

// ---------------------------------------------------------------------------
// Prep: At[bn][n][k] = bf16(A[bn][k][n]); 32*128*128 bf16 = 1 MB into d_ws.
// ---------------------------------------------------------------------------
__global__ __launch_bounds__(256) void prep_at_kernel(
        const float* __restrict__ A, unsigned short* __restrict__ At)
{
    int g   = blockIdx.x * 256 + threadIdx.x;   // 65536 total
    int bn  = g >> 11;
    int rem = g & 2047;
    int kc  = rem >> 7;                         // k octet
    int n   = rem & 127;

    const float* src = A + bn * 16384 + kc * 8 * 128 + n;
    unsigned h[4];
    #pragma unroll
    for (int j = 0; j < 4; ++j) {
        unsigned short lo = f2bf(src[(2 * j    ) * 128]);
        unsigned short hi = f2bf(src[(2 * j + 1) * 128]);
        h[j] = (unsigned)lo | ((unsigned)hi << 16);
    }
    uint4 pk = make_uint4(h[0], h[1], h[2], h[3]);
    *(uint4*)(At + bn * 16384 + n * 128 + kc * 8) = pk;
}

// ---------------------------------------------------------------------------
// Main: grid 2048 = 32 bn x 64 mt-groups; bn fixed per block -> At block in
// registers once. 256 threads = 4 waves in a 2x2 split: wave (wm,wn) owns
// 16 rows x 64 cols of each 32x128 tile (bq[4][4]=64 VGPR, acc[4]=16).
// Natural VGPR ~120 with __launch_bounds__(256,4) (128 cap, unified
// VGPR+AGPR file) -> 16 waves/SIMD-group = 4 blocks/CU co-resident: four
// independently-staggered barrier groups cover each other's vmcnt drains.
// (R3 lesson: (512,8) forced 64 total regs -> spill -> +160 MB HBM traffic.)
// v tile: 32x128 f32, double-buffered LDS (32 KB) via global_load_lds x4;
// XOR-swizzle (row&7)<<4 applied BOTH on pre-swizzled global source and on
// the ds_read byte offset.
// ---------------------------------------------------------------------------
__global__ __launch_bounds__(256, 4) void trans_main_kernel(
        const float* __restrict__ v,  const float* __restrict__ dx,
        const unsigned short* __restrict__ At, const float* __restrict__ Bm,
        const float* __restrict__ bsc, float* __restrict__ out)
{
    __shared__ float lds[2][32 * 128];          // 32 KB

    const int tid = threadIdx.x;
    const int wid = tid >> 6;
    const int l   = tid & 63;
    const int lr  = l & 15;
    const int lq  = l >> 4;
    const int wm  = wid >> 1;                   // 0..1 (16-row half)
    const int wn  = wid & 1;                    // 0..1 (64-col half)
    const int bn     = blockIdx.x >> 6;         // 0..31
    const int mtbase = blockIdx.x & 63;         // 0..63

    // ---- At block -> registers, once. b-frag: B[k=lq*8+j][n=col] ----
    bf16x8 bq[4][4];
    const unsigned short* atb = At + bn * 16384 + (wn * 64 + lr) * 128 + lq * 8;
    #pragma unroll
    for (int kq = 0; kq < 4; ++kq)
        #pragma unroll
        for (int ni = 0; ni < 4; ++ni)
            bq[kq][ni] = *(const bf16x8*)(atb + ni * 16 * 128 + kq * 32);

    // ---- epilogue constants (bn fixed for whole block) ----
    const float bias = *bsc;
    const int col0 = bn * 128 + wn * 64;
    float2 bc[4];
    #pragma unroll
    for (int ni = 0; ni < 4; ++ni)
        bc[ni] = *(const float2*)(Bm + 2 * (col0 + ni * 16 + lr));

    // ---- async stage of one 32x128 tile (pre-swizzled source) ----
    auto stage = [&](int buf, int mt) {
        const float* src = v + (size_t)mt * 32 * 4096 + bn * 128;
        #pragma unroll
        for (int it = 0; it < 4; ++it) {
            int c16  = it * 256 + tid;          // 16B-chunk index in tile
            int row  = c16 >> 5;                // 32 chunks per 512B row
            int off  = (c16 & 31) << 4;         // byte offset within row
            int soff = off ^ ((row & 7) << 4);  // inverse-swizzled source
            const float* g = src + (size_t)row * 4096 + (soff >> 2);
            __builtin_amdgcn_global_load_lds(
                (const __attribute__((address_space(1))) unsigned int*)g,
                (__attribute__((address_space(3))) unsigned int*)
                    &lds[buf][c16 * 4],
                16, 0, 0);
        }
    };

    f32x4 acc[4];
    #pragma unroll
    for (int ni = 0; ni < 4; ++ni)
        acc[ni] = (f32x4){0.f, 0.f, 0.f, 0.f};

    stage(0, mtbase);
    __syncthreads();                            // buf0 ready

    for (int j = 0; j < 8; ++j) {
        const int mt = j * 64 + mtbase;         // 0..511 row-tile index
        if (j + 1 < 8) stage((j + 1) & 1, (j + 1) * 64 + mtbase);

        // ---- compute from lds[j&1] ----
        const char* Lb = (const char*)&lds[j & 1][0];
        const int row = wm * 16 + lr;
        const int rb  = row * 512;
        const int m   = (row & 7) << 4;
        #pragma unroll
        for (int kq = 0; kq < 4; ++kq) {
            const int base = kq * 128 + lq * 32;
            float4 f0 = *(const float4*)(Lb + rb + ((base     ) ^ m));
            float4 f1 = *(const float4*)(Lb + rb + ((base + 16) ^ m));
            union { bf16x8 vv; unsigned short s[8]; } u;
            u.s[0] = f2bf(f0.x); u.s[1] = f2bf(f0.y);
            u.s[2] = f2bf(f0.z); u.s[3] = f2bf(f0.w);
            u.s[4] = f2bf(f1.x); u.s[5] = f2bf(f1.y);
            u.s[6] = f2bf(f1.z); u.s[7] = f2bf(f1.w);
            #pragma unroll
            for (int ni = 0; ni < 4; ++ni)
                acc[ni] = __builtin_amdgcn_mfma_f32_16x16x32_bf16(
                              u.vv, bq[kq][ni], acc[ni], 0, 0, 0);
        }

        // ---- epilogue: + dx @ B^T + b, ReLU, store; reset acc ----
        #pragma unroll
        for (int jj = 0; jj < 4; ++jj) {
            const int rowg = mt * 32 + wm * 16 + lq * 4 + jj;
            const float2 d = *(const float2*)(dx + 2 * rowg);
            float* orow = out + (size_t)rowg * 4096 + col0 + lr;
            #pragma unroll
            for (int ni = 0; ni < 4; ++ni) {
                float val = acc[ni][jj] + d.x * bc[ni].x + d.y * bc[ni].y + bias;
                orow[ni * 16] = fmaxf(val, 0.0f);
            }
        }
        #pragma unroll
        for (int ni = 0; ni < 4; ++ni)
            acc[ni] = (f32x4){0.f, 0.f, 0.f, 0.f};

        __syncthreads();    // all reads of lds[j&1] done; next stage complete
    }
}

// ---------------------------------------------------------------------------
extern "C" void kernel_launch(void* const* d_in, const int* in_sizes, int n_in,
                              void* d_out, int out_size, void* d_ws, size_t ws_size,
                              hipStream_t stream)
{
    const float* v  = (const float*)d_in[0];   // [16384, 4096]
    const float* dx = (const float*)d_in[1];   // [16384, 2]
    const float* A  = (const float*)d_in[2];   // [32, 128, 128]
    const float* Bm = (const float*)d_in[3];   // [4096, 2]
    const float* b  = (const float*)d_in[4];   // scalar

    unsigned short* At = (unsigned short*)d_ws; // 1 MB: [32][128 n][128 k] bf16

    prep_at_kernel<<<dim3(256), dim3(256), 0, stream>>>(A, At);
    trans_main_kernel<<<dim3(2048), dim3(256), 0, stream>>>(v, dx, At, Bm, b,
                                                            (float*)d_out);
}